// Round 2
// 290.402 us; speedup vs baseline: 1.0534x; 1.0534x over previous
//
#include <hip/hip_runtime.h>
#include <math.h>

typedef unsigned short u16;
typedef unsigned int u32;
typedef __attribute__((ext_vector_type(2))) float f32x2;

#define CAP 64      // adjacency row stride (self at slot 0, up to 63 neighbors, padded to x8 with zero-row)
#define BSHIFT 9    // 512 nodes per bucket -> nb = ceil(n/512) <= 256 for n <= 131072
#define BCAP 9600   // records per bucket region (mean 8163 -> 16 sigma headroom)

// bf16 <-> f32 helpers
__device__ inline float bf2f(u16 u) {
    union { u32 i; float f; } c; c.i = ((u32)u) << 16; return c.f;
}
__device__ inline u32 cvtpk(float lo, float hi) {  // HW RNE pack: {hi|lo} bf16 pair
    u32 r;
    asm("v_cvt_pk_bf16_f32 %0, %1, %2" : "=v"(r) : "v"(lo), "v"(hi));
    return r;
}
__device__ inline f32x2 unp(u32 d) {  // dword of 2 bf16 -> f32x2 (lo, hi)
    union { u32 u; float f; } lo, hi;
    lo.u = d << 16;
    hi.u = d & 0xFFFF0000u;
    f32x2 r; r.x = lo.f; r.y = hi.f;
    return r;
}
__device__ inline f32x2 shflx2(f32x2 val, int m) {  // xor-shuffle both halves (DS pipe)
    union { f32x2 v; int u[2]; } a; a.v = val;
    a.u[0] = __shfl_xor(a.u[0], m);
    a.u[1] = __shfl_xor(a.u[1], m);
    return a.v;
}

// ---------------- adjacency build: two-pass LDS bucket sort ----------------
// (round-7 post-mortem: device-scope atomics resolve at the memory-side
// coherence point -> per-edge random global atomics were the bottleneck;
// bucket sort replaces them with per-(block,bucket) reservations.)

__global__ void zero_gcount_kernel(int* __restrict__ gcount) {
    gcount[threadIdx.x] = 0;
}

__global__ __launch_bounds__(256) void bucket_kernel(const int* __restrict__ src,
                                                     const int* __restrict__ dst,
                                                     int* __restrict__ gcount,
                                                     int2* __restrict__ bucketbuf,
                                                     int e, int nb) {
    __shared__ int lh[256];
    int tid = threadIdx.x;
    if (tid < nb) lh[tid] = 0;
    __syncthreads();
    int per = (e + gridDim.x - 1) / gridDim.x;
    int i0 = blockIdx.x * per;
    int i1 = i0 + per; if (i1 > e) i1 = e;
    for (int i = i0 + tid; i < i1; i += 256)
        atomicAdd(&lh[dst[i] >> BSHIFT], 1);
    __syncthreads();
    if (tid < nb) {
        int c = lh[tid];
        lh[tid] = (c > 0) ? atomicAdd(&gcount[tid], c) : 0;
    }
    __syncthreads();
    for (int i = i0 + tid; i < i1; i += 256) {
        int d = dst[i], s = src[i];
        int b = d >> BSHIFT;
        int pos = atomicAdd(&lh[b], 1);  // LDS cursor -> unique global slot
        if (pos < BCAP) bucketbuf[(size_t)b * BCAP + pos] = make_int2(d, s);
    }
}

// csrify: adjacency row layout (round-10): slot 0 = self, slots 1..nr-1 = neighbors,
// slots nr..pad-1 = n (zero-row index). cnt[node] = nr (includes self). This removes
// ALL per-batch masking/cndmask from the gather inner loop.
__global__ __launch_bounds__(256) void csrify_kernel(const int2* __restrict__ bucketbuf,
                                                     const int* __restrict__ gcount,
                                                     int* __restrict__ cnt,
                                                     float* __restrict__ dis,
                                                     int* __restrict__ srcs2d, int n) {
    __shared__ int lc[512];
    int b = blockIdx.x;
    int tid = threadIdx.x;
    int node_lo = b << BSHIFT;
    #pragma unroll
    for (int q = tid; q < 512; q += 256) lc[q] = 0;
    __syncthreads();
    int m = gcount[b]; if (m > BCAP) m = BCAP;
    const int2* bp = bucketbuf + (size_t)b * BCAP;
    for (int i = tid; i < m; i += 256) {
        int2 r = bp[i];
        int k = atomicAdd(&lc[r.x - node_lo], 1);
        if (k < CAP - 1) srcs2d[((size_t)r.x << 6) + k + 1] = r.y;  // slot 0 reserved for self
    }
    __syncthreads();
    for (int q = tid; q < 512; q += 256) {
        int node = node_lo + q;
        if (node < n) {
            int c = lc[q];
            int nr = (c < CAP - 1 ? c : CAP - 1) + 1;   // rows incl. self, <= 64
            cnt[node] = nr;
            dis[node] = rsqrtf((float)c + 1.0f);        // true degree + self loop
            int* row = srcs2d + ((size_t)node << 6);
            row[0] = node;                               // self loop
            int pr = (nr + 7) & ~7;
            for (int t = nr; t < pr; ++t) row[t] = n;    // pad -> zero row
        }
    }
}

// ---------------- register-tiled GEMM: Y[n, OSTR] = dis[r] * (X[n,IN] @ W[IN,OUT]) ----------------
// block = 256 threads -> 64 rows x 64 (padded) cols; thread = 4x4 tile.
// k-loop kept at unroll 1 (round-3 post-mortem: full unroll -> 256 VGPR spill).
// Epilogue scales row r by dis[r] (source-side GCN normalization folded in),
// packs with v_cvt_pk_bf16_f32 (HW RNE). Row r == n is written as all zeros
// (the gather's padding target). Cols OUT_F..OSTR-1 are exact zeros.

__device__ inline float4 load4(const float* p) { return *(const float4*)p; }
__device__ inline float4 load4(const u16* p) {
    ushort4 u = *(const ushort4*)p;
    return make_float4(bf2f(u.x), bf2f(u.y), bf2f(u.z), bf2f(u.w));
}

template<typename XT, int IN_F, int OUT_F, int OSTR>
__global__ __launch_bounds__(256) void gemm_scale_kernel(const XT* __restrict__ X,
                                                         const float* __restrict__ W,
                                                         const float* __restrict__ dis,
                                                         u16* __restrict__ Y, int n) {
    constexpr int PC = 64;  // padded col count (== OSTR)
    __shared__ float Wl[IN_F * PC];
    int tid = threadIdx.x;
    for (int idx = tid; idx < IN_F * PC; idx += 256) {
        int k = idx / PC, c = idx % PC;
        Wl[idx] = (c < OUT_F) ? W[k * OUT_F + c] : 0.f;
    }
    __syncthreads();
    int tx = tid & 15;   // col group (4 cols)
    int ty = tid >> 4;   // row group (4 rows)
    int r0 = blockIdx.x * 64 + ty * 4;
    int c0 = tx * 4;
    const XT* xr[4];
    #pragma unroll
    for (int i = 0; i < 4; ++i) {
        int r = r0 + i;
        if (r >= n) r = n - 1;
        xr[i] = X + (size_t)r * IN_F;
    }
    float acc[4][4] = {};
    const float4* Wv = (const float4*)Wl;  // index: k*16 + tx
    #pragma unroll 1
    for (int k = 0; k < IN_F; k += 4) {
        float4 xv[4];
        #pragma unroll
        for (int i = 0; i < 4; ++i) xv[i] = load4(xr[i] + k);
        #pragma unroll
        for (int j = 0; j < 4; ++j) {
            float4 wv = Wv[(k + j) * 16 + tx];
            #pragma unroll
            for (int i = 0; i < 4; ++i) {
                float xs = (j == 0) ? xv[i].x : (j == 1) ? xv[i].y : (j == 2) ? xv[i].z : xv[i].w;
                acc[i][0] = fmaf(xs, wv.x, acc[i][0]);
                acc[i][1] = fmaf(xs, wv.y, acc[i][1]);
                acc[i][2] = fmaf(xs, wv.z, acc[i][2]);
                acc[i][3] = fmaf(xs, wv.w, acc[i][3]);
            }
        }
    }
    #pragma unroll
    for (int i = 0; i < 4; ++i) {
        int r = r0 + i;
        if (r < n) {
            float sc = dis[r];
            u32 p0 = cvtpk(acc[i][0] * sc, acc[i][1] * sc);
            u32 p1 = cvtpk(acc[i][2] * sc, acc[i][3] * sc);
            *(uint2*)(Y + (size_t)r * OSTR + c0) = make_uint2(p0, p1);
        } else if (r == n) {
            *(uint2*)(Y + (size_t)r * OSTR + c0) = make_uint2(0u, 0u);  // zero row for gather padding
        }
    }
}

// ---------------- wide-load gather: one wave per node, 8 rows per load instr ----------------
// Round-9: vector-mem INSTRUCTION bound fix (lane = (j<<3)|c; 1 dwordx4 = 8 rows).
// Round-10 post-mortem: still VALU-instruction bound (VALUBusy 86%, HBM 26%, MfmaUtil 0).
// Fixes: (1) self-loop + zero-row padding moved into srcs2d -> no cmp/cndmask in loop;
// (2) f32x2 accumulators -> v_pk_add_f32 (12 ops/16B instead of 16, reduction adds halved);
// (3) 32-bit saddr offsets; (4) v_cvt_pk_bf16_f32 epilogue pack; (5) __expf/__logf.
// Shuffles stay on the idle DS pipe (bpermute/swizzle), NOT permlane (VALU is the bottleneck).
//   FINAL=0: H[i,:] = relu(di * rowsum + b)        -> bf16, 64 cols
//   FINAL=1: out[i,:] = log_softmax(di*rowsum + b) -> f32, first 40 cols

template<int FINAL>
__global__ __launch_bounds__(256) void gatherw_kernel(const u16* __restrict__ v,
                                                      const int* __restrict__ cnt,
                                                      const int* __restrict__ srcs2d,
                                                      const float* __restrict__ dis,
                                                      const float* __restrict__ bias,
                                                      u16* __restrict__ outb,
                                                      float* __restrict__ outf, int n) {
    int wid = __builtin_amdgcn_readfirstlane((blockIdx.x * blockDim.x + threadIdx.x) >> 6);
    int lane = threadIdx.x & 63;
    if (wid >= n) return;  // wave-uniform
    int nrows = __builtin_amdgcn_readfirstlane(cnt[wid]);  // includes self
    int padded = (nrows + 7) & ~7;                         // list pre-padded to x8 with zero-row
    int j = lane >> 3;                         // row within batch (0..7)
    int c = lane & 7;                          // col-group (8 bf16 each)
    int idx_all = srcs2d[((size_t)wid << 6) + lane];  // whole adjacency row, 256 B
    f32x2 acc[4];
    #pragma unroll
    for (int i = 0; i < 4; ++i) { acc[i].x = 0.f; acc[i].y = 0.f; }
    int baddr = j << 2;                        // bpermute byte addr for entry (k + j)
    u32 coff = (u32)(c << 3);                  // element offset of this lane's col group
    for (int k = 0; k < padded; k += 8) {
        int sj = __builtin_amdgcn_ds_bpermute(baddr, idx_all);
        baddr += 32;
        const uint4* rp = (const uint4*)(v + (((u32)sj << 6) + coff));
        uint4 a = *rp;                         // 16 B = 8 bf16 of row sj
        acc[0] += unp(a.x);
        acc[1] += unp(a.y);
        acc[2] += unp(a.z);
        acc[3] += unp(a.w);
    }
    #pragma unroll
    for (int i = 0; i < 4; ++i) {              // reduce over j (all lanes end with totals)
        acc[i] += shflx2(acc[i], 8);
        acc[i] += shflx2(acc[i], 16);
        acc[i] += shflx2(acc[i], 32);
    }
    float di = dis[wid];
    if (FINAL == 0) {
        const f32x2* bp2 = (const f32x2*)(bias + (c << 3));
        f32x2 o[4];
        #pragma unroll
        for (int i = 0; i < 4; ++i) {
            f32x2 b = bp2[i];
            o[i].x = fmaxf(fmaf(di, acc[i].x, b.x), 0.f);
            o[i].y = fmaxf(fmaf(di, acc[i].y, b.y), 0.f);
        }
        if (j == 0) {
            uint4 p = make_uint4(cvtpk(o[0].x, o[0].y), cvtpk(o[1].x, o[1].y),
                                 cvtpk(o[2].x, o[2].y), cvtpk(o[3].x, o[3].y));
            *(uint4*)(outb + (((size_t)wid) << 6) + (c << 3)) = p;
        }
    } else {
        bool act = c < 5;                      // col-groups 0..4 = cols 0..39
        int cb = act ? c : 0;
        const f32x2* bp2 = (const f32x2*)(bias + (cb << 3));
        float zz[8];
        #pragma unroll
        for (int i = 0; i < 4; ++i) {
            f32x2 b = bp2[i];
            zz[2 * i]     = act ? fmaf(di, acc[i].x, b.x) : -INFINITY;
            zz[2 * i + 1] = act ? fmaf(di, acc[i].y, b.y) : -INFINITY;
        }
        float mx = zz[0];
        #pragma unroll
        for (int i = 1; i < 8; ++i) mx = fmaxf(mx, zz[i]);
        mx = fmaxf(mx, __shfl_xor(mx, 1));
        mx = fmaxf(mx, __shfl_xor(mx, 2));
        mx = fmaxf(mx, __shfl_xor(mx, 4));
        float ssum = 0.f;
        if (act) {
            #pragma unroll
            for (int i = 0; i < 8; ++i) ssum += __expf(zz[i] - mx);
        }
        ssum += __shfl_xor(ssum, 1);
        ssum += __shfl_xor(ssum, 2);
        ssum += __shfl_xor(ssum, 4);
        float ls = __logf(ssum) + mx;
        if (j == 0 && act) {
            float* op = outf + (size_t)wid * 40 + (c << 3);
            *(float4*)op = make_float4(zz[0] - ls, zz[1] - ls, zz[2] - ls, zz[3] - ls);
            *(float4*)(op + 4) = make_float4(zz[4] - ls, zz[5] - ls, zz[6] - ls, zz[7] - ls);
        }
    }
}

// ---------------- launch ----------------

extern "C" void kernel_launch(void* const* d_in, const int* in_sizes, int n_in,
                              void* d_out, int out_size, void* d_ws, size_t ws_size,
                              hipStream_t stream) {
    const float* x  = (const float*)d_in[0];
    const int*   ei = (const int*)d_in[1];   // [2, E] int32
    const float* W1 = (const float*)d_in[2]; // [128, 64]
    const float* b1 = (const float*)d_in[3]; // [64]
    const float* W2 = (const float*)d_in[4]; // [64, 40]
    const float* b2 = (const float*)d_in[5]; // [40]
    float* out = (float*)d_out;              // [n, 40]

    const int n = in_sizes[0] / 128;
    const int e = in_sizes[1] / 2;
    const int* src = ei;
    const int* dst = ei + e;
    const int nb = (n + 511) >> BSHIFT;      // buckets of 512 nodes, <= 256

    // workspace layout (~54 MB):
    //   gcount[256] i32 | cnt[n] i32 | dis[n] f32 |
    //   bucketbuf[nb*BCAP] int2 (overlaid after csrify: A bf16 (n+1)*64 — xw-scaled,
    //                            row n = zeros, the gather padding target)
    //   srcs2d[n*64] i32 | B[n*64] bf16 (H)
    int* gcount = (int*)d_ws;
    int* cnt    = gcount + 256;
    float* dis  = (float*)(cnt + n);
    int2* bucketbuf = (int2*)(dis + n);
    u16* A      = (u16*)bucketbuf;           // (n+1)*64*2 B <= nb*BCAP*8 B
    int* srcs2d = (int*)(bucketbuf + (size_t)nb * BCAP);
    u16* B      = (u16*)(srcs2d + ((size_t)n << 6));

    const int T = 256;
    const int gblocks = (n * 64 + T - 1) / T;
    const int mblocks = (n >> 6) + 1;        // covers rows 0..n (row n = zero row)

    // --- adjacency build (bucket sort, no per-edge global atomics) ---
    zero_gcount_kernel<<<1, 256, 0, stream>>>(gcount);
    bucket_kernel<<<448, 256, 0, stream>>>(src, dst, gcount, bucketbuf, e, nb);
    csrify_kernel<<<nb, 256, 0, stream>>>(bucketbuf, gcount, cnt, dis, srcs2d, n);

    // --- layer 1: A = dis .* (x@W1) (bf16, 64 cols, +zero row) ; H = relu(di*rowsum + b1) ---
    gemm_scale_kernel<float, 128, 64, 64>
        <<<mblocks, 256, 0, stream>>>(x, W1, dis, A, n);
    gatherw_kernel<0><<<gblocks, T, 0, stream>>>(A, cnt, srcs2d, dis, b1, B, nullptr, n);

    // --- layer 2: A = dis .* (H@W2) (bf16, 64-col padded, cols 40-63 = 0, +zero row) ;
    //              out = log_softmax(di*rowsum + b2) ---
    gemm_scale_kernel<u16, 64, 40, 64>
        <<<mblocks, 256, 0, stream>>>(B, W2, dis, A, n);
    gatherw_kernel<1><<<gblocks, T, 0, stream>>>(A, cnt, srcs2d, dis, b2, nullptr, out, n);
}

// Round 3
// 289.460 us; speedup vs baseline: 1.0569x; 1.0033x over previous
//
#include <hip/hip_runtime.h>
#include <math.h>

typedef unsigned short u16;
typedef unsigned int u32;
typedef __attribute__((ext_vector_type(2))) float f32x2;

#define CAP 64      // adjacency row stride (self at slot 0, up to 63 neighbors, padded to x8 with zero-row)
#define BSHIFT 9    // 512 nodes per bucket -> nb = ceil(n/512) <= 256 for n <= 131072
#define BCAP 9600   // records per bucket region (mean 8163 -> 16 sigma headroom)

// bf16 <-> f32 helpers
__device__ inline float bf2f(u16 u) {
    union { u32 i; float f; } c; c.i = ((u32)u) << 16; return c.f;
}
__device__ inline u32 cvtpk(float lo, float hi) {  // HW RNE pack: {hi|lo} bf16 pair
    u32 r;
    asm("v_cvt_pk_bf16_f32 %0, %1, %2" : "=v"(r) : "v"(lo), "v"(hi));
    return r;
}
__device__ inline f32x2 unp(u32 d) {  // dword of 2 bf16 -> f32x2 (lo, hi)
    union { u32 u; float f; } lo, hi;
    lo.u = d << 16;
    hi.u = d & 0xFFFF0000u;
    f32x2 r; r.x = lo.f; r.y = hi.f;
    return r;
}
__device__ inline f32x2 shflx2(f32x2 val, int m) {  // xor-shuffle both halves (DS pipe)
    union { f32x2 v; int u[2]; } a; a.v = val;
    a.u[0] = __shfl_xor(a.u[0], m);
    a.u[1] = __shfl_xor(a.u[1], m);
    return a.v;
}

// ---------------- adjacency build: two-pass LDS bucket sort ----------------
// (round-7 post-mortem: device-scope atomics resolve at the memory-side
// coherence point -> per-edge random global atomics were the bottleneck;
// bucket sort replaces them with per-(block,bucket) reservations.)

__global__ void zero_gcount_kernel(int* __restrict__ gcount) {
    gcount[threadIdx.x] = 0;
}

__global__ __launch_bounds__(256) void bucket_kernel(const int* __restrict__ src,
                                                     const int* __restrict__ dst,
                                                     int* __restrict__ gcount,
                                                     int2* __restrict__ bucketbuf,
                                                     int e, int nb) {
    __shared__ int lh[256];
    int tid = threadIdx.x;
    if (tid < nb) lh[tid] = 0;
    __syncthreads();
    int per = (e + gridDim.x - 1) / gridDim.x;
    int i0 = blockIdx.x * per;
    int i1 = i0 + per; if (i1 > e) i1 = e;
    for (int i = i0 + tid; i < i1; i += 256)
        atomicAdd(&lh[dst[i] >> BSHIFT], 1);
    __syncthreads();
    if (tid < nb) {
        int c = lh[tid];
        lh[tid] = (c > 0) ? atomicAdd(&gcount[tid], c) : 0;
    }
    __syncthreads();
    for (int i = i0 + tid; i < i1; i += 256) {
        int d = dst[i], s = src[i];
        int b = d >> BSHIFT;
        int pos = atomicAdd(&lh[b], 1);  // LDS cursor -> unique global slot
        if (pos < BCAP) bucketbuf[(size_t)b * BCAP + pos] = make_int2(d, s);
    }
}

// csrify: adjacency row layout: slot 0 = self, slots 1..nr-1 = neighbors,
// slots nr..pad-1 = n (zero-row index). cnt[node] = nr (includes self). This removes
// ALL per-batch masking/cndmask from the gather inner loop.
__global__ __launch_bounds__(256) void csrify_kernel(const int2* __restrict__ bucketbuf,
                                                     const int* __restrict__ gcount,
                                                     int* __restrict__ cnt,
                                                     float* __restrict__ dis,
                                                     int* __restrict__ srcs2d, int n) {
    __shared__ int lc[512];
    int b = blockIdx.x;
    int tid = threadIdx.x;
    int node_lo = b << BSHIFT;
    #pragma unroll
    for (int q = tid; q < 512; q += 256) lc[q] = 0;
    __syncthreads();
    int m = gcount[b]; if (m > BCAP) m = BCAP;
    const int2* bp = bucketbuf + (size_t)b * BCAP;
    for (int i = tid; i < m; i += 256) {
        int2 r = bp[i];
        int k = atomicAdd(&lc[r.x - node_lo], 1);
        if (k < CAP - 1) srcs2d[((size_t)r.x << 6) + k + 1] = r.y;  // slot 0 reserved for self
    }
    __syncthreads();
    for (int q = tid; q < 512; q += 256) {
        int node = node_lo + q;
        if (node < n) {
            int c = lc[q];
            int nr = (c < CAP - 1 ? c : CAP - 1) + 1;   // rows incl. self, <= 64
            cnt[node] = nr;
            dis[node] = rsqrtf((float)c + 1.0f);        // true degree + self loop
            int* row = srcs2d + ((size_t)node << 6);
            row[0] = node;                               // self loop
            int pr = (nr + 7) & ~7;
            for (int t = nr; t < pr; ++t) row[t] = n;    // pad -> zero row
        }
    }
}

// ---------------- register-tiled GEMM: Y[n, OSTR] = dis[r] * (X[n,IN] @ W[IN,OUT]) ----------------
// block = 256 threads -> 64 rows x 64 (padded) cols; thread = 4x4 tile.
// Round-11 post-mortem: VALUBusy 28%, occupancy 28%, HBM 9% -> LATENCY-bound serial
// chain {load xv -> vmcnt(0) -> 64 FMA}. Fix: double-buffered xv/xn register
// prefetch so k-step FMAs overlap (k+4) global loads. Prefetch index wraps to 0
// on the last step (branch-free, no OOB).
// Epilogue scales row r by dis[r], packs with v_cvt_pk_bf16_f32 (HW RNE).
// Row r == n is written as all zeros (the gather's padding target).

__device__ inline float4 load4(const float* p) { return *(const float4*)p; }
__device__ inline float4 load4(const u16* p) {
    ushort4 u = *(const ushort4*)p;
    return make_float4(bf2f(u.x), bf2f(u.y), bf2f(u.z), bf2f(u.w));
}

template<typename XT, int IN_F, int OUT_F, int OSTR>
__global__ __launch_bounds__(256) void gemm_scale_kernel(const XT* __restrict__ X,
                                                         const float* __restrict__ W,
                                                         const float* __restrict__ dis,
                                                         u16* __restrict__ Y, int n) {
    constexpr int PC = 64;  // padded col count (== OSTR)
    __shared__ float Wl[IN_F * PC];
    int tid = threadIdx.x;
    for (int idx = tid; idx < IN_F * PC; idx += 256) {
        int k = idx / PC, c = idx % PC;
        Wl[idx] = (c < OUT_F) ? W[k * OUT_F + c] : 0.f;
    }
    __syncthreads();
    int tx = tid & 15;   // col group (4 cols)
    int ty = tid >> 4;   // row group (4 rows)
    int r0 = blockIdx.x * 64 + ty * 4;
    int c0 = tx * 4;
    const XT* xr[4];
    #pragma unroll
    for (int i = 0; i < 4; ++i) {
        int r = r0 + i;
        if (r >= n) r = n - 1;
        xr[i] = X + (size_t)r * IN_F;
    }
    float acc[4][4] = {};
    const float4* Wv = (const float4*)Wl;  // index: k*16 + tx
    float4 xv[4], xn[4];
    #pragma unroll
    for (int i = 0; i < 4; ++i) xv[i] = load4(xr[i]);          // k = 0
    #pragma unroll 1
    for (int k = 0; k < IN_F; k += 4) {
        int kn = (k + 4 < IN_F) ? (k + 4) : 0;                 // wrap: safe dummy prefetch
        #pragma unroll
        for (int i = 0; i < 4; ++i) xn[i] = load4(xr[i] + kn); // in flight during FMAs
        #pragma unroll
        for (int j = 0; j < 4; ++j) {
            float4 wv = Wv[(k + j) * 16 + tx];
            #pragma unroll
            for (int i = 0; i < 4; ++i) {
                float xs = (j == 0) ? xv[i].x : (j == 1) ? xv[i].y : (j == 2) ? xv[i].z : xv[i].w;
                acc[i][0] = fmaf(xs, wv.x, acc[i][0]);
                acc[i][1] = fmaf(xs, wv.y, acc[i][1]);
                acc[i][2] = fmaf(xs, wv.z, acc[i][2]);
                acc[i][3] = fmaf(xs, wv.w, acc[i][3]);
            }
        }
        #pragma unroll
        for (int i = 0; i < 4; ++i) xv[i] = xn[i];
    }
    #pragma unroll
    for (int i = 0; i < 4; ++i) {
        int r = r0 + i;
        if (r < n) {
            float sc = dis[r];
            u32 p0 = cvtpk(acc[i][0] * sc, acc[i][1] * sc);
            u32 p1 = cvtpk(acc[i][2] * sc, acc[i][3] * sc);
            *(uint2*)(Y + (size_t)r * OSTR + c0) = make_uint2(p0, p1);
        } else if (r == n) {
            *(uint2*)(Y + (size_t)r * OSTR + c0) = make_uint2(0u, 0u);  // zero row for gather padding
        }
    }
}

// ---------------- wide-load gather: one wave per node, 8 rows per load instr ----------------
// Round-9: vector-mem INSTRUCTION bound fix (lane = (j<<3)|c; 1 dwordx4 = 8 rows).
// Round-10: self-loop + zero-row padding in srcs2d (no cmp/cndmask in loop);
// f32x2 accumulators -> v_pk_add_f32; v_cvt_pk_bf16_f32 pack; __expf/__logf.
// Round-11: counters noise-contaminated across containers (VALUBusy 59 vs 80%) -> untouched.
//   FINAL=0: H[i,:] = relu(di * rowsum + b)        -> bf16, 64 cols
//   FINAL=1: out[i,:] = log_softmax(di*rowsum + b) -> f32, first 40 cols

template<int FINAL>
__global__ __launch_bounds__(256) void gatherw_kernel(const u16* __restrict__ v,
                                                      const int* __restrict__ cnt,
                                                      const int* __restrict__ srcs2d,
                                                      const float* __restrict__ dis,
                                                      const float* __restrict__ bias,
                                                      u16* __restrict__ outb,
                                                      float* __restrict__ outf, int n) {
    int wid = __builtin_amdgcn_readfirstlane((blockIdx.x * blockDim.x + threadIdx.x) >> 6);
    int lane = threadIdx.x & 63;
    if (wid >= n) return;  // wave-uniform
    int nrows = __builtin_amdgcn_readfirstlane(cnt[wid]);  // includes self
    int padded = (nrows + 7) & ~7;                         // list pre-padded to x8 with zero-row
    int j = lane >> 3;                         // row within batch (0..7)
    int c = lane & 7;                          // col-group (8 bf16 each)
    int idx_all = srcs2d[((size_t)wid << 6) + lane];  // whole adjacency row, 256 B
    f32x2 acc[4];
    #pragma unroll
    for (int i = 0; i < 4; ++i) { acc[i].x = 0.f; acc[i].y = 0.f; }
    int baddr = j << 2;                        // bpermute byte addr for entry (k + j)
    u32 coff = (u32)(c << 3);                  // element offset of this lane's col group
    for (int k = 0; k < padded; k += 8) {
        int sj = __builtin_amdgcn_ds_bpermute(baddr, idx_all);
        baddr += 32;
        const uint4* rp = (const uint4*)(v + (((u32)sj << 6) + coff));
        uint4 a = *rp;                         // 16 B = 8 bf16 of row sj
        acc[0] += unp(a.x);
        acc[1] += unp(a.y);
        acc[2] += unp(a.z);
        acc[3] += unp(a.w);
    }
    #pragma unroll
    for (int i = 0; i < 4; ++i) {              // reduce over j (all lanes end with totals)
        acc[i] += shflx2(acc[i], 8);
        acc[i] += shflx2(acc[i], 16);
        acc[i] += shflx2(acc[i], 32);
    }
    float di = dis[wid];
    if (FINAL == 0) {
        const f32x2* bp2 = (const f32x2*)(bias + (c << 3));
        f32x2 o[4];
        #pragma unroll
        for (int i = 0; i < 4; ++i) {
            f32x2 b = bp2[i];
            o[i].x = fmaxf(fmaf(di, acc[i].x, b.x), 0.f);
            o[i].y = fmaxf(fmaf(di, acc[i].y, b.y), 0.f);
        }
        if (j == 0) {
            uint4 p = make_uint4(cvtpk(o[0].x, o[0].y), cvtpk(o[1].x, o[1].y),
                                 cvtpk(o[2].x, o[2].y), cvtpk(o[3].x, o[3].y));
            *(uint4*)(outb + (((size_t)wid) << 6) + (c << 3)) = p;
        }
    } else {
        bool act = c < 5;                      // col-groups 0..4 = cols 0..39
        int cb = act ? c : 0;
        const f32x2* bp2 = (const f32x2*)(bias + (cb << 3));
        float zz[8];
        #pragma unroll
        for (int i = 0; i < 4; ++i) {
            f32x2 b = bp2[i];
            zz[2 * i]     = act ? fmaf(di, acc[i].x, b.x) : -INFINITY;
            zz[2 * i + 1] = act ? fmaf(di, acc[i].y, b.y) : -INFINITY;
        }
        float mx = zz[0];
        #pragma unroll
        for (int i = 1; i < 8; ++i) mx = fmaxf(mx, zz[i]);
        mx = fmaxf(mx, __shfl_xor(mx, 1));
        mx = fmaxf(mx, __shfl_xor(mx, 2));
        mx = fmaxf(mx, __shfl_xor(mx, 4));
        float ssum = 0.f;
        if (act) {
            #pragma unroll
            for (int i = 0; i < 8; ++i) ssum += __expf(zz[i] - mx);
        }
        ssum += __shfl_xor(ssum, 1);
        ssum += __shfl_xor(ssum, 2);
        ssum += __shfl_xor(ssum, 4);
        float ls = __logf(ssum) + mx;
        if (j == 0 && act) {
            float* op = outf + (size_t)wid * 40 + (c << 3);
            *(float4*)op = make_float4(zz[0] - ls, zz[1] - ls, zz[2] - ls, zz[3] - ls);
            *(float4*)(op + 4) = make_float4(zz[4] - ls, zz[5] - ls, zz[6] - ls, zz[7] - ls);
        }
    }
}

// ---------------- launch ----------------

extern "C" void kernel_launch(void* const* d_in, const int* in_sizes, int n_in,
                              void* d_out, int out_size, void* d_ws, size_t ws_size,
                              hipStream_t stream) {
    const float* x  = (const float*)d_in[0];
    const int*   ei = (const int*)d_in[1];   // [2, E] int32
    const float* W1 = (const float*)d_in[2]; // [128, 64]
    const float* b1 = (const float*)d_in[3]; // [64]
    const float* W2 = (const float*)d_in[4]; // [64, 40]
    const float* b2 = (const float*)d_in[5]; // [40]
    float* out = (float*)d_out;              // [n, 40]

    const int n = in_sizes[0] / 128;
    const int e = in_sizes[1] / 2;
    const int* src = ei;
    const int* dst = ei + e;
    const int nb = (n + 511) >> BSHIFT;      // buckets of 512 nodes, <= 256

    // workspace layout (~54 MB):
    //   gcount[256] i32 | cnt[n] i32 | dis[n] f32 |
    //   bucketbuf[nb*BCAP] int2 (overlaid after csrify: A bf16 (n+1)*64 — xw-scaled,
    //                            row n = zeros, the gather padding target)
    //   srcs2d[n*64] i32 | B[n*64] bf16 (H)
    int* gcount = (int*)d_ws;
    int* cnt    = gcount + 256;
    float* dis  = (float*)(cnt + n);
    int2* bucketbuf = (int2*)(dis + n);
    u16* A      = (u16*)bucketbuf;           // (n+1)*64*2 B <= nb*BCAP*8 B
    int* srcs2d = (int*)(bucketbuf + (size_t)nb * BCAP);
    u16* B      = (u16*)(srcs2d + ((size_t)n << 6));

    const int T = 256;
    const int gblocks = (n * 64 + T - 1) / T;
    const int mblocks = (n >> 6) + 1;        // covers rows 0..n (row n = zero row)

    // --- adjacency build (bucket sort, no per-edge global atomics) ---
    zero_gcount_kernel<<<1, 256, 0, stream>>>(gcount);
    bucket_kernel<<<448, 256, 0, stream>>>(src, dst, gcount, bucketbuf, e, nb);
    csrify_kernel<<<nb, 256, 0, stream>>>(bucketbuf, gcount, cnt, dis, srcs2d, n);

    // --- layer 1: A = dis .* (x@W1) (bf16, 64 cols, +zero row) ; H = relu(di*rowsum + b1) ---
    gemm_scale_kernel<float, 128, 64, 64>
        <<<mblocks, 256, 0, stream>>>(x, W1, dis, A, n);
    gatherw_kernel<0><<<gblocks, T, 0, stream>>>(A, cnt, srcs2d, dis, b1, B, nullptr, n);

    // --- layer 2: A = dis .* (H@W2) (bf16, 64-col padded, cols 40-63 = 0, +zero row) ;
    //              out = log_softmax(di*rowsum + b2) ---
    gemm_scale_kernel<u16, 64, 40, 64>
        <<<mblocks, 256, 0, stream>>>(B, W2, dis, A, n);
    gatherw_kernel<1><<<gblocks, T, 0, stream>>>(A, cnt, srcs2d, dis, b2, nullptr, out, n);
}